// Round 7
// baseline (784.597 us; speedup 1.0000x reference)
//
#include <hip/hip_runtime.h>
#include <hip/hip_bf16.h>
#include <math.h>

// SwinTransformer3D block, bf16-MFMA, fragment-ordered LDS + fused MLP.
// B=8 T=8 H=56 W=56 C=128, window (2,7,7) -> N=98 (pad 112), shift (1,3,3),
// HEADS=4, d=32. TOK = 2048*98 = 200704 tokens.
//
// ws layout (bytes):
//   P0 = 0          : xw / attnO (bf16 TOK*128), reused serially
//   P1 = 51,381,248 : q  bf16 [bwh*98+n][32]
//   P2 = P1+51,381,248 : k  bf16 same
//   P3 = P2+51,381,248 : Vt bf16 [bwh*32+d][112]
//   PW = 256,902,144 : bf16 weights (qkv/proj/fc1/fc2)
// Residual y lives in d_out (fp32); mlp_k does in-place add.

#define TOK 200704
#define SCALE_Q 0.17677669529663687f

typedef __attribute__((ext_vector_type(8))) short bf16x8;
typedef __attribute__((ext_vector_type(4))) float f32x4;

__device__ __forceinline__ short f2b(float f) {
    __hip_bfloat16 h = __float2bfloat16(f);
    return *reinterpret_cast<short*>(&h);
}

// tanh-form GELU via hardware exp; |err| vs exact erf-GELU < 3e-3, washes out
// far below the 0.109 output threshold after fc2.
__device__ __forceinline__ float gelu_f(float v) {
    float u = 1.5957691216057308f * (v + 0.044715f * v * v * v);
    return v / (1.f + __expf(-u));
}

// token (win*98+n) -> float offset of its ORIGINAL spatial position
// (window reverse + roll-back; also the gather map for LN1+roll+partition).
__device__ __forceinline__ size_t spatial_off(int tok) {
    int win = tok / 98;
    int n = tok - win * 98;
    int b = win >> 8;
    int widx = win & 255;
    int t_blk = widx >> 6;
    int h_blk = (widx >> 3) & 7;
    int w_blk = widx & 7;
    int tt = (n >= 49) ? 1 : 0;
    int r = n - tt * 49;
    int hh = r / 7;
    int ww = r - hh * 7;
    int t = t_blk * 2 + tt;
    int hc = h_blk * 7 + hh;
    int wc = w_blk * 7 + ww;
    int tf = (t + 1) & 7;
    int hf = hc + 3; if (hf >= 56) hf -= 56;
    int wf = wc + 3; if (wf >= 56) wf -= 56;
    return ((((size_t)b * 8 + tf) * 56 + hf) * 56 + wf) * 128;
}

__global__ __launch_bounds__(256) void cvt_k(const float* __restrict__ s,
                                             short* __restrict__ d, int n) {
    int i = blockIdx.x * 256 + threadIdx.x;
    if (i < n) d[i] = f2b(s[i]);
}

// LN1 + shifted roll + window partition. One wave per token.
__global__ __launch_bounds__(256) void ln_k(const float* __restrict__ src,
                                            const float* __restrict__ g,
                                            const float* __restrict__ b,
                                            short* __restrict__ dst) {
    int tok = blockIdx.x * 4 + (threadIdx.x >> 6);
    int lane = threadIdx.x & 63;
    const float* sp = src + spatial_off(tok);
    float2 v = *(const float2*)(sp + lane * 2);
    float s = v.x + v.y;
    float q = v.x * v.x + v.y * v.y;
#pragma unroll
    for (int o = 32; o > 0; o >>= 1) {
        s += __shfl_xor(s, o);
        q += __shfl_xor(q, o);
    }
    float mean = s * 0.0078125f;
    float var = q * 0.0078125f - mean * mean;
    float rstd = rsqrtf(var + 1e-5f);
    float2 gv = *(const float2*)(g + lane * 2);
    float2 bv = *(const float2*)(b + lane * 2);
    short2 o2;
    o2.x = f2b((v.x - mean) * rstd * gv.x + bv.x);
    o2.y = f2b((v.y - mean) * rstd * gv.y + bv.y);
    *(short2*)(dst + (size_t)tok * 128 + lane * 2) = o2;
}

// bf16 MFMA GEMM, 128x128 tile, 4 waves, K=128.
// LDS is FRAGMENT-ORDERED: fragment block fb (= 16-row band) holds 64 lanes
// x 16B contiguously -> every ds_read_b128/ds_write_b128 is base+lane*16,
// conflict-free. As/Ws = 8KB each.
// MODE 0: QKV -> q,k (bf16 [bwh*98+n][32], q scaled) + Vt (bf16 [bwh*32+d][112])
// MODE 1: proj + x residual, spatial scatter -> y (fp32, = d_out)
template <int MODE>
__global__ __launch_bounds__(256) void mgemm(const short* __restrict__ A,
                                             const short* __restrict__ Wt,
                                             const float* __restrict__ bias,
                                             void* __restrict__ Optr,
                                             const float* __restrict__ E0,
                                             short* __restrict__ O2,
                                             short* __restrict__ O3) {
    __shared__ short As[4096];
    __shared__ short Ws[4096];
    const int tid = threadIdx.x;
    const int nb = blockIdx.x, mb = blockIdx.y;
    const int lane = tid & 63;
    const int wid = tid >> 6;
    const int wr = wid >> 1, wc = wid & 1;
    const int l15 = lane & 15, kg = lane >> 4;
    const int KDIM = 128;

    f32x4 zf = {0.f, 0.f, 0.f, 0.f};
    f32x4 acc[4][4];
#pragma unroll
    for (int i = 0; i < 4; i++)
#pragma unroll
        for (int j = 0; j < 4; j++) acc[i][j] = zf;

    const int sr = tid >> 2;          // 0..63
    const int sc = (tid & 3) * 8;     // 0,8,16,24
    const int sl8 = ((sr & 15) + 16 * (tid & 3)) * 8;  // lane slot (shorts)
    const short* Ag = A + (size_t)(mb * 128 + sr) * KDIM + sc;
    const short* Wg = Wt + (size_t)(nb * 128 + sr) * KDIM + sc;
    const size_t half = (size_t)64 * KDIM;

    for (int k0 = 0; k0 < KDIM; k0 += 32) {
        *(bf16x8*)&As[(sr >> 4) * 512 + sl8] = *(const bf16x8*)(Ag + k0);
        *(bf16x8*)&As[((sr >> 4) + 4) * 512 + sl8] = *(const bf16x8*)(Ag + half + k0);
        *(bf16x8*)&Ws[(sr >> 4) * 512 + sl8] = *(const bf16x8*)(Wg + k0);
        *(bf16x8*)&Ws[((sr >> 4) + 4) * 512 + sl8] = *(const bf16x8*)(Wg + half + k0);
        __syncthreads();
        bf16x8 af[4], bfr[4];
#pragma unroll
        for (int mi = 0; mi < 4; mi++)
            af[mi] = *(const bf16x8*)&As[(wr * 4 + mi) * 512 + lane * 8];
#pragma unroll
        for (int ni = 0; ni < 4; ni++)
            bfr[ni] = *(const bf16x8*)&Ws[(wc * 4 + ni) * 512 + lane * 8];
#pragma unroll
        for (int mi = 0; mi < 4; mi++)
#pragma unroll
            for (int ni = 0; ni < 4; ni++)
                acc[mi][ni] = __builtin_amdgcn_mfma_f32_16x16x32_bf16(
                    af[mi], bfr[ni], acc[mi][ni], 0, 0, 0);
        __syncthreads();
    }

#pragma unroll
    for (int mi = 0; mi < 4; mi++) {
#pragma unroll
        for (int r = 0; r < 4; r++) {
            int gr = mb * 128 + wr * 64 + mi * 16 + kg * 4 + r;
            size_t so = 0;
            if constexpr (MODE == 1) so = spatial_off(gr);
#pragma unroll
            for (int ni = 0; ni < 4; ni++) {
                int gc = nb * 128 + wc * 64 + ni * 16 + l15;
                float v = acc[mi][ni][r] + bias[gc];
                if constexpr (MODE == 0) {
                    int which = gc >> 7;
                    int head = (gc >> 5) & 3;
                    int dd = gc & 31;
                    int lwin = gr / 98;
                    int n = gr - lwin * 98;
                    size_t bwh = (size_t)lwin * 4 + head;
                    if (which == 0) {
                        ((short*)Optr)[(bwh * 98 + n) * 32 + dd] = f2b(v * SCALE_Q);
                    } else if (which == 1) {
                        O2[(bwh * 98 + n) * 32 + dd] = f2b(v);
                    } else {
                        O3[(bwh * 32 + dd) * 112 + n] = f2b(v);
                    }
                } else {
                    float* Of = (float*)Optr;
                    Of[so + gc] = v + E0[so + gc];
                }
            }
        }
    }
}

// Fused MLP: per 128-row tile of y (= d_out, spatial-linear):
//   LN2 (in-block stats) -> Xs(frag LDS) ; 4 chunks of
//   { fc1(K=128) -> GELU -> Hs(frag LDS) -> fc2 partial accumulate } ;
//   out = y + fc2 + b2 (in-place RMW).
// LDS: Xs 32KB + Hs 32KB + Wb 16KB = 80KB -> 2 blocks/CU.
__global__ __launch_bounds__(256) void mlp_k(float* __restrict__ out,
                                             const float* __restrict__ g2,
                                             const float* __restrict__ b2ln,
                                             const short* __restrict__ w1,
                                             const float* __restrict__ b1,
                                             const short* __restrict__ w2,
                                             const float* __restrict__ b2) {
    __shared__ short Xs[16384];
    __shared__ short Hs[16384];
    __shared__ short Wb[8192];
    const int tid = threadIdx.x;
    const int mb = blockIdx.x;
    const int lane = tid & 63;
    const int wid = tid >> 6;
    const int wr = wid >> 1, wc = wid & 1;
    const int l15 = lane & 15, kg = lane >> 4;

    // ---- prologue: y tile -> LN2 -> Xs fragments ----
    {
        const int r = tid >> 1;
        const int c0 = (tid & 1) * 64;
        const float* yp = out + (size_t)(mb * 128 + r) * 128 + c0;
        float4 yv[16];
        float s = 0.f, q = 0.f;
#pragma unroll
        for (int j = 0; j < 16; j++) {
            yv[j] = *(const float4*)(yp + 4 * j);
            s += yv[j].x + yv[j].y + yv[j].z + yv[j].w;
            q += yv[j].x * yv[j].x + yv[j].y * yv[j].y +
                 yv[j].z * yv[j].z + yv[j].w * yv[j].w;
        }
        s += __shfl_xor(s, 1);
        q += __shfl_xor(q, 1);
        float mean = s * 0.0078125f;
        float var = q * 0.0078125f - mean * mean;
        float rstd = rsqrtf(var + 1e-5f);
#pragma unroll
        for (int j = 0; j < 8; j++) {
            int c = c0 + 8 * j;
            float va[8] = {yv[2 * j].x, yv[2 * j].y, yv[2 * j].z, yv[2 * j].w,
                           yv[2 * j + 1].x, yv[2 * j + 1].y, yv[2 * j + 1].z,
                           yv[2 * j + 1].w};
            bf16x8 o;
#pragma unroll
            for (int e = 0; e < 8; e++)
                o[e] = f2b((va[e] - mean) * rstd * g2[c + e] + b2ln[c + e]);
            int fbx = (r >> 4) * 4 + (c >> 5);
            int lp = (r & 15) + 16 * ((c >> 3) & 3);
            *(bf16x8*)&Xs[fbx * 512 + lp * 8] = o;
        }
    }

    f32x4 zf = {0.f, 0.f, 0.f, 0.f};
    f32x4 acc2[4][4];
#pragma unroll
    for (int i = 0; i < 4; i++)
#pragma unroll
        for (int j = 0; j < 4; j++) acc2[i][j] = zf;

    const int sr = tid >> 2;
    const int sc = (tid & 3) * 8;
    const int slp = (sr & 15) + 16 * (tid & 3);  // lane within fragment

    for (int nc = 0; nc < 4; nc++) {
        f32x4 acc1[4][4];
#pragma unroll
        for (int i = 0; i < 4; i++)
#pragma unroll
            for (int j = 0; j < 4; j++) acc1[i][j] = zf;

        // ---- fc1: W = w1 rows nc*128..+127, K=128 in 2 halves ----
        for (int kh = 0; kh < 2; kh++) {
            __syncthreads();  // protect Wb from previous readers
#pragma unroll
            for (int p = 0; p < 2; p++)
#pragma unroll
                for (int qq = 0; qq < 2; qq++) {
                    int r2 = sr + 64 * p;
                    int c2 = sc + 32 * qq;
                    bf16x8 w = *(const bf16x8*)(w1 + (size_t)(nc * 128 + r2) * 128 +
                                                kh * 64 + c2);
                    *(bf16x8*)&Wb[((r2 >> 4) * 2 + qq) * 512 + slp * 8] = w;
                }
            __syncthreads();
#pragma unroll
            for (int ks = 0; ks < 2; ks++) {
                bf16x8 af[4], bfr[4];
#pragma unroll
                for (int mi = 0; mi < 4; mi++)
                    af[mi] = *(const bf16x8*)&Xs[((wr * 4 + mi) * 4 + kh * 2 + ks) * 512 +
                                                 lane * 8];
#pragma unroll
                for (int ni = 0; ni < 4; ni++)
                    bfr[ni] = *(const bf16x8*)&Wb[((wc * 4 + ni) * 2 + ks) * 512 +
                                                  lane * 8];
#pragma unroll
                for (int mi = 0; mi < 4; mi++)
#pragma unroll
                    for (int ni = 0; ni < 4; ni++)
                        acc1[mi][ni] = __builtin_amdgcn_mfma_f32_16x16x32_bf16(
                            af[mi], bfr[ni], acc1[mi][ni], 0, 0, 0);
            }
        }

        // ---- GELU + bias -> Hs fragments (prev-chunk readers are >=2 barriers back)
#pragma unroll
        for (int mi = 0; mi < 4; mi++)
#pragma unroll
            for (int ni = 0; ni < 4; ni++) {
                int cc = wc * 64 + ni * 16 + l15;
                float bb = b1[nc * 128 + cc];
#pragma unroll
                for (int r = 0; r < 4; r++) {
                    int rr = wr * 64 + mi * 16 + kg * 4 + r;
                    float v = gelu_f(acc1[mi][ni][r] + bb);
                    Hs[((rr >> 4) * 4 + (cc >> 5)) * 512 +
                       ((rr & 15) + 16 * ((cc >> 3) & 3)) * 8 + (cc & 7)] = f2b(v);
                }
            }

        // ---- fc2 partial: A = Hs, W = w2[:, nc*128..], K=128 in 2 halves ----
        for (int kh2 = 0; kh2 < 2; kh2++) {
            __syncthreads();  // Wb protect + Hs visibility
#pragma unroll
            for (int p = 0; p < 2; p++)
#pragma unroll
                for (int qq = 0; qq < 2; qq++) {
                    int r2 = sr + 64 * p;
                    int c2 = sc + 32 * qq;
                    bf16x8 w = *(const bf16x8*)(w2 + (size_t)r2 * 512 + nc * 128 +
                                                kh2 * 64 + c2);
                    *(bf16x8*)&Wb[((r2 >> 4) * 2 + qq) * 512 + slp * 8] = w;
                }
            __syncthreads();
#pragma unroll
            for (int ks = 0; ks < 2; ks++) {
                bf16x8 pa[4], bfr[4];
#pragma unroll
                for (int mi = 0; mi < 4; mi++)
                    pa[mi] = *(const bf16x8*)&Hs[((wr * 4 + mi) * 4 + kh2 * 2 + ks) * 512 +
                                                 lane * 8];
#pragma unroll
                for (int ni = 0; ni < 4; ni++)
                    bfr[ni] = *(const bf16x8*)&Wb[((wc * 4 + ni) * 2 + ks) * 512 +
                                                  lane * 8];
#pragma unroll
                for (int mi = 0; mi < 4; mi++)
#pragma unroll
                    for (int ni = 0; ni < 4; ni++)
                        acc2[mi][ni] = __builtin_amdgcn_mfma_f32_16x16x32_bf16(
                            pa[mi], bfr[ni], acc2[mi][ni], 0, 0, 0);
            }
        }
    }

    // ---- epilogue: out = y + fc2 + b2 (in-place RMW) ----
#pragma unroll
    for (int mi = 0; mi < 4; mi++)
#pragma unroll
        for (int r = 0; r < 4; r++) {
            int gr = mb * 128 + wr * 64 + mi * 16 + kg * 4 + r;
#pragma unroll
            for (int ni = 0; ni < 4; ni++) {
                int gc = wc * 64 + ni * 16 + l15;
                size_t o = (size_t)gr * 128 + gc;
                out[o] = acc2[mi][ni][r] + b2[gc] + out[o];
            }
        }
}

// Attention: block = window (4 waves = 4 heads). N=98 padded to 112. Unchanged
// from round 6 (passed; below the top-line cost).
__global__ __launch_bounds__(256) void attn_k(const short* __restrict__ Qb,
                                              const short* __restrict__ Kb,
                                              const short* __restrict__ Vt,
                                              const float* __restrict__ rpb,
                                              short* __restrict__ O) {
    __shared__ short P_lds[4][16 * 136];
    __shared__ float rbias[4][508];
    const int win = blockIdx.x;
    const int tid = threadIdx.x;
    const int head = tid >> 6;
    const int lane = tid & 63;
    const int l15 = lane & 15, kg = lane >> 4;
    const size_t bwh = (size_t)win * 4 + head;
    const int widx = win & 255;
    const int t_blk = widx >> 6, h_blk = (widx >> 3) & 7, w_blk = widx & 7;
    short* Pw = P_lds[head];

    for (int i = lane; i < 507; i += 64) rbias[head][i] = rpb[i * 4 + head];
#pragma unroll
    for (int i = 0; i < 4; i++) {
        int idx = lane * 4 + i;
        Pw[(idx >> 4) * 136 + 112 + (idx & 15)] = 0;
    }

    const short* Kg = Kb + bwh * 3136;
    bf16x8 kf[7];
#pragma unroll
    for (int b = 0; b < 7; b++)
        kf[b] = *(const bf16x8*)(Kg + (b * 16 + l15) * 32 + kg * 8);
    const short* Vg = Vt + bwh * 3584;
    bf16x8 vf[2][4];
#pragma unroll
    for (int nt = 0; nt < 2; nt++)
#pragma unroll
        for (int ks = 0; ks < 4; ks++)
            vf[nt][ks] = *(const bf16x8*)(Vg + (nt * 16 + l15) * 112 + ks * 32 + kg * 8);

    int cm_t[7], cm_h[7], cm_w[7], creg[7];
    bool cvalid[7];
#pragma unroll
    for (int b = 0; b < 7; b++) {
        int n = b * 16 + l15;
        cvalid[b] = (n < 98);
        int nn = cvalid[b] ? n : 0;
        int tt = (nn >= 49) ? 1 : 0;
        int r = nn - tt * 49;
        int hh = r / 7;
        int ww = r - hh * 7;
        cm_t[b] = tt; cm_h[b] = hh; cm_w[b] = ww;
        int ct = (t_blk == 3) ? (1 + tt) : 0;
        int ch = (h_blk == 7) ? ((hh <= 3) ? 1 : 2) : 0;
        int cw = (w_blk == 7) ? ((ww <= 3) ? 1 : 2) : 0;
        creg[b] = ct * 9 + ch * 3 + cw;
    }

    const short* Qg = Qb + bwh * 3136;
    f32x4 zf = {0.f, 0.f, 0.f, 0.f};

    for (int a = 0; a < 7; a++) {
        bf16x8 qf = *(const bf16x8*)(Qg + (a * 16 + l15) * 32 + kg * 8);
        f32x4 s[7];
#pragma unroll
        for (int b = 0; b < 7; b++)
            s[b] = __builtin_amdgcn_mfma_f32_16x16x32_bf16(qf, kf[b], zf, 0, 0, 0);

        float p[7][4], mx[4], sm[4];
#pragma unroll
        for (int r = 0; r < 4; r++) {
            int m = a * 16 + kg * 4 + r;
            int mm = (m < 98) ? m : 0;
            int tt = (mm >= 49) ? 1 : 0;
            int rr = mm - tt * 49;
            int hh = rr / 7;
            int ww = rr - hh * 7;
            int ct = (t_blk == 3) ? (1 + tt) : 0;
            int ch = (h_blk == 7) ? ((hh <= 3) ? 1 : 2) : 0;
            int cw = (w_blk == 7) ? ((ww <= 3) ? 1 : 2) : 0;
            int rreg = ct * 9 + ch * 3 + cw;
            float mxv = -1e30f;
#pragma unroll
            for (int b = 0; b < 7; b++) {
                float v;
                if (cvalid[b]) {
                    int bidx = (tt - cm_t[b] + 1) * 169 + (hh - cm_h[b] + 6) * 13 +
                               (ww - cm_w[b] + 6);
                    v = s[b][r] + rbias[head][bidx] +
                        ((rreg == creg[b]) ? 0.f : -100.f);
                } else {
                    v = -1e30f;
                }
                p[b][r] = v;
                mxv = fmaxf(mxv, v);
            }
            mx[r] = mxv;
        }
#pragma unroll
        for (int r = 0; r < 4; r++) {
#pragma unroll
            for (int off = 1; off < 16; off <<= 1)
                mx[r] = fmaxf(mx[r], __shfl_xor(mx[r], off));
        }
#pragma unroll
        for (int r = 0; r < 4; r++) {
            float ss = 0.f;
#pragma unroll
            for (int b = 0; b < 7; b++) {
                float e = __expf(p[b][r] - mx[r]);
                p[b][r] = e;
                ss += e;
            }
            sm[r] = ss;
        }
#pragma unroll
        for (int r = 0; r < 4; r++) {
#pragma unroll
            for (int off = 1; off < 16; off <<= 1) sm[r] += __shfl_xor(sm[r], off);
        }
#pragma unroll
        for (int r = 0; r < 4; r++) {
            float inv = 1.f / sm[r];
#pragma unroll
            for (int b = 0; b < 7; b++)
                Pw[(kg * 4 + r) * 136 + b * 16 + l15] = f2b(p[b][r] * inv);
        }
        asm volatile("" ::: "memory");

        bf16x8 pa[4];
#pragma unroll
        for (int ks = 0; ks < 4; ks++)
            pa[ks] = *(const bf16x8*)&Pw[l15 * 136 + ks * 32 + kg * 8];
        f32x4 o0 = zf, o1 = zf;
#pragma unroll
        for (int ks = 0; ks < 4; ks++) {
            o0 = __builtin_amdgcn_mfma_f32_16x16x32_bf16(pa[ks], vf[0][ks], o0, 0, 0, 0);
            o1 = __builtin_amdgcn_mfma_f32_16x16x32_bf16(pa[ks], vf[1][ks], o1, 0, 0, 0);
        }
        asm volatile("" ::: "memory");
#pragma unroll
        for (int r = 0; r < 4; r++) {
            int m = a * 16 + kg * 4 + r;
            if (m < 98) {
                size_t base = ((size_t)win * 98 + m) * 128 + head * 32;
                O[base + l15] = f2b(o0[r]);
                O[base + 16 + l15] = f2b(o1[r]);
            }
        }
    }
}

extern "C" void kernel_launch(void* const* d_in, const int* in_sizes, int n_in,
                              void* d_out, int out_size, void* d_ws, size_t ws_size,
                              hipStream_t stream) {
    const float* x      = (const float*)d_in[0];
    const float* ln1_g  = (const float*)d_in[2];
    const float* ln1_b  = (const float*)d_in[3];
    const float* qkv_w  = (const float*)d_in[4];
    const float* qkv_b  = (const float*)d_in[5];
    const float* rpb    = (const float*)d_in[6];
    const float* proj_w = (const float*)d_in[7];
    const float* proj_b = (const float*)d_in[8];
    const float* ln2_g  = (const float*)d_in[9];
    const float* ln2_b  = (const float*)d_in[10];
    const float* fc1_w  = (const float*)d_in[11];
    const float* fc1_b  = (const float*)d_in[12];
    const float* fc2_w  = (const float*)d_in[13];
    const float* fc2_b  = (const float*)d_in[14];
    float* out = (float*)d_out;   // residual y lives here

    char* ws = (char*)d_ws;
    const size_t P1 = 51381248;          // q
    const size_t P2 = P1 + 51381248;     // k
    const size_t P3 = P2 + 51381248;     // Vt
    const size_t PW = 256902144;         // weights

    short* xw    = (short*)ws;           // also attnO (serial reuse)
    short* q     = (short*)(ws + P1);
    short* k     = (short*)(ws + P2);
    short* Vt    = (short*)(ws + P3);
    short* wq    = (short*)(ws + PW);            // 49152 elems
    short* wp    = (short*)(ws + PW + 98304);    // 16384
    short* w1    = (short*)(ws + PW + 131072);   // 65536
    short* w2    = (short*)(ws + PW + 262144);   // 65536

    cvt_k<<<(49152 + 255) / 256, 256, 0, stream>>>(qkv_w, wq, 49152);
    cvt_k<<<(16384 + 255) / 256, 256, 0, stream>>>(proj_w, wp, 16384);
    cvt_k<<<(65536 + 255) / 256, 256, 0, stream>>>(fc1_w, w1, 65536);
    cvt_k<<<(65536 + 255) / 256, 256, 0, stream>>>(fc2_w, w2, 65536);

    // LN1 + roll + window partition
    ln_k<<<TOK / 4, 256, 0, stream>>>(x, ln1_g, ln1_b, xw);
    // QKV GEMM (M=200704, N=384, K=128) -> q, k, Vt
    mgemm<0><<<dim3(3, 1568), 256, 0, stream>>>(xw, wq, qkv_b, (void*)q,
                                                nullptr, k, Vt);
    // attention -> attnO (reuses xw region)
    attn_k<<<2048, 256, 0, stream>>>(q, k, Vt, rpb, xw);
    // proj + residual -> y (= d_out, fp32), spatial scatter
    mgemm<1><<<dim3(1, 1568), 256, 0, stream>>>(xw, wp, proj_b, (void*)out,
                                                x, nullptr, nullptr);
    // fused LN2 + fc1 + GELU + fc2 + residual (in-place on d_out)
    mlp_k<<<1568, 256, 0, stream>>>(out, ln2_g, ln2_b, w1, fc1_b, w2, fc2_b);
}